// Round 1
// baseline (203.896 us; speedup 1.0000x reference)
//
#include <hip/hip_runtime.h>
#include <stdint.h>

typedef unsigned short u16;
typedef short short4v __attribute__((ext_vector_type(4)));
typedef short short8v __attribute__((ext_vector_type(8)));
typedef float float4v __attribute__((ext_vector_type(4)));

#define AS1(p) ((__attribute__((address_space(1))) void*)(p))
#define AS3(p) ((__attribute__((address_space(3))) void*)(p))

#define MFMA32(a, b, c) __builtin_amdgcn_mfma_f32_16x16x32_bf16(a, b, c, 0, 0, 0)

static __device__ __forceinline__ float4v MFMA16(short4v a, short4v b, float4v c) {
#if __has_builtin(__builtin_amdgcn_mfma_f32_16x16x16bf16_1k)
  return __builtin_amdgcn_mfma_f32_16x16x16bf16_1k(a, b, c, 0, 0, 0);
#else
  float4v d;
  asm volatile("v_mfma_f32_16x16x16_bf16 %0, %1, %2, %3\n\ts_nop 7\n\ts_nop 3"
               : "=v"(d)
               : "v"(a), "v"(b), "v"(c));
  return d;
#endif
}

static __device__ __forceinline__ u16 f2bf(float f) {
  uint32_t u = __builtin_bit_cast(uint32_t, f);
  u += 0x7FFFu + ((u >> 16) & 1u);
  return (u16)(u >> 16);
}

// ---------------- f32 -> bf16 casts ----------------

__global__ __launch_bounds__(256) void cast1_k(const float* __restrict__ s, u16* __restrict__ d) {
  const int i = (blockIdx.x * 256 + threadIdx.x) * 4;
  float4v v = *(const float4v*)(s + i);
  short4v o;
#pragma unroll
  for (int j = 0; j < 4; j++) o[j] = (short)f2bf(v[j]);
  *(short4v*)(d + i) = o;
}

__global__ __launch_bounds__(256) void cast4_k(const float* __restrict__ s0, const float* __restrict__ s1,
                                               const float* __restrict__ s2, const float* __restrict__ s3,
                                               u16* __restrict__ d0, u16* __restrict__ d1,
                                               u16* __restrict__ d2, u16* __restrict__ d3) {
  const float* s;
  u16* d;
  switch (blockIdx.y) {
    case 0: s = s0; d = d0; break;
    case 1: s = s1; d = d1; break;
    case 2: s = s2; d = d2; break;
    default: s = s3; d = d3; break;
  }
  const int i = (blockIdx.x * 256 + threadIdx.x) * 4;
  float4v v = *(const float4v*)(s + i);
  short4v o;
#pragma unroll
  for (int j = 0; j < 4; j++) o[j] = (short)f2bf(v[j]);
  *(short4v*)(d + i) = o;
}

// ---------------- GEMM: C[m,n] = sum_k A[m,k]*B[n,k] + bias[n] ----------------
// A: M x 1024 bf16 row-major.  B: 1024 x 1024 bf16 row-major ("B^T" layout).
// 128x128 tile, BK=32, 4 waves (2x2), 4x4 16x16 fragments per wave.
// grid.y selects segment (of 3) + n-block (of 8).

template <int OUTF32>
__global__ __launch_bounds__(256) void gemm_bt(
    const u16* __restrict__ A,
    const u16* __restrict__ B0, const u16* __restrict__ B1, const u16* __restrict__ B2,
    const float* __restrict__ bias0, const float* __restrict__ bias1, const float* __restrict__ bias2,
    void* __restrict__ C0, void* __restrict__ C1, void* __restrict__ C2) {
  constexpr int K = 1024;
  __shared__ u16 As[128 * 32];
  __shared__ u16 Bs[128 * 32];

  const int t = threadIdx.x;
  const int lane = t & 63, wid = t >> 6;
  const int wr = wid >> 1, wc = wid & 1;
  const int lr = lane & 15, g = lane >> 4;

  const int seg = blockIdx.y >> 3, nb = blockIdx.y & 7, mb = blockIdx.x;
  const u16* B = seg == 0 ? B0 : (seg == 1 ? B1 : B2);
  const float* bias = seg == 0 ? bias0 : (seg == 1 ? bias1 : bias2);
  void* C = seg == 0 ? C0 : (seg == 1 ? C1 : C2);

  const u16* Ap = A + (size_t)mb * 128 * K;
  const u16* Bp = B + (size_t)nb * 128 * K;

  float4v z = {0.f, 0.f, 0.f, 0.f};
  float4v acc[4][4];
#pragma unroll
  for (int i = 0; i < 4; i++)
#pragma unroll
    for (int j = 0; j < 4; j++) acc[i][j] = z;

  // 16B chunk c covers (row = c/4, col = (c%4)*8) of a [128][32] tile.
  const int r0 = t >> 2, c0 = (t & 3) * 8;
  const int r1 = (t + 256) >> 2, c1 = ((t + 256) & 3) * 8;

  for (int k0 = 0; k0 < K; k0 += 32) {
    __syncthreads();
    __builtin_amdgcn_global_load_lds(AS1(Ap + (size_t)r0 * K + k0 + c0), AS3(As + t * 8), 16, 0, 0);
    __builtin_amdgcn_global_load_lds(AS1(Ap + (size_t)r1 * K + k0 + c1), AS3(As + (t + 256) * 8), 16, 0, 0);
    __builtin_amdgcn_global_load_lds(AS1(Bp + (size_t)r0 * K + k0 + c0), AS3(Bs + t * 8), 16, 0, 0);
    __builtin_amdgcn_global_load_lds(AS1(Bp + (size_t)r1 * K + k0 + c1), AS3(Bs + (t + 256) * 8), 16, 0, 0);
    __syncthreads();

    short8v af[4], bfr[4];
#pragma unroll
    for (int mi = 0; mi < 4; mi++) af[mi] = *(const short8v*)(As + (wr * 64 + mi * 16 + lr) * 32 + g * 8);
#pragma unroll
    for (int ni = 0; ni < 4; ni++) bfr[ni] = *(const short8v*)(Bs + (wc * 64 + ni * 16 + lr) * 32 + g * 8);
#pragma unroll
    for (int mi = 0; mi < 4; mi++)
#pragma unroll
      for (int ni = 0; ni < 4; ni++) acc[mi][ni] = MFMA32(af[mi], bfr[ni], acc[mi][ni]);
  }

  const int colb = nb * 128 + wc * 64;
  const int rowb = mb * 128 + wr * 64;
#pragma unroll
  for (int ni = 0; ni < 4; ni++) {
    const int col = colb + ni * 16 + lr;
    const float bv = bias[col];
#pragma unroll
    for (int mi = 0; mi < 4; mi++) {
      const int row0 = rowb + mi * 16 + g * 4;
      float4v a = acc[mi][ni];
      if (OUTF32) {
        float* Cf = (float*)C;
#pragma unroll
        for (int r = 0; r < 4; r++) Cf[(size_t)(row0 + r) * 1024 + col] = a[r] + bv;
      } else {
        u16* Cb = (u16*)C;
#pragma unroll
        for (int r = 0; r < 4; r++) Cb[(size_t)(row0 + r) * 1024 + col] = f2bf(a[r] + bv);
      }
    }
  }
}

// ---------------- Flash attention ----------------
// Q,K,V: (4096 tokens, 1024) bf16, head slice = cols [a*64, a*64+64).
// Block: 64 q-rows of one (b,a); 4 waves x 16 rows. KV tile = 32 keys.
// Swapped S^T = mfma(K,Q): lane holds S[kr=(g*4+r)][q=lr] -> softmax state per lane = per q.
// PV: O^T = V^T * P^T via 16x16x16 mfma; A-frag = V (scalar swizzled LDS reads),
// B-frag = P^T packed from softmax registers (layout matches exactly).

__global__ __launch_bounds__(256) void attn_fwd(const u16* __restrict__ Qm, const u16* __restrict__ Km,
                                                const u16* __restrict__ Vm, u16* __restrict__ Om) {
  __shared__ u16 Ks[32 * 64];
  __shared__ u16 Vs[32 * 64];

  const int t = threadIdx.x;
  const int lane = t & 63, w = t >> 6;
  const int lr = lane & 15, g = lane >> 4;
  const int qb = blockIdx.x, pair = blockIdx.y;
  const int b = pair >> 4, a = pair & 15;

  const int qrow = qb * 64 + w * 16 + lr;
  const size_t qoff = ((size_t)(b * 1024 + qrow)) * 1024 + a * 64;
  const short8v qf0 = *(const short8v*)(Qm + qoff + g * 8);
  const short8v qf1 = *(const short8v*)(Qm + qoff + 32 + g * 8);

  float4v z = {0.f, 0.f, 0.f, 0.f};
  float4v ot[4];
#pragma unroll
  for (int i = 0; i < 4; i++) ot[i] = z;
  float mrun = -3.0e38f, lsum = 0.f;
  const float csc = 1.44269504088896f / 8.0f;  // log2(e)/sqrt(64)

  const u16* Kb = Km + ((size_t)b * 1024) * 1024 + a * 64;
  const u16* Vb = Vm + ((size_t)b * 1024) * 1024 + a * 64;

  // staging: thread t covers 16B chunk (row=t/8, chunk=t%8) of [32][64]
  const int srow = t >> 3, sc = t & 7;
  const int kcol = (sc ^ (srow & 7)) * 8;                  // K: XOR-swizzled source chunk
  const int vcol = (sc ^ (((srow >> 2) & 3) << 1)) * 8;    // V: 16-elem group XOR by (j>>2)&3

  for (int kt = 0; kt < 1024; kt += 32) {
    __syncthreads();
    __builtin_amdgcn_global_load_lds(AS1(Kb + (size_t)(kt + srow) * 1024 + kcol), AS3(Ks + t * 8), 16, 0, 0);
    __builtin_amdgcn_global_load_lds(AS1(Vb + (size_t)(kt + srow) * 1024 + vcol), AS3(Vs + t * 8), 16, 0, 0);
    __syncthreads();

    // S^T tiles: 2 x (16 kr x 16 q)
    float4v st[2];
#pragma unroll
    for (int jt = 0; jt < 2; jt++) {
      float4v s = z;
      const int row = jt * 16 + lr;
#pragma unroll
      for (int ks = 0; ks < 2; ks++) {
        const int baddr = (row * 128 + (ks * 4 + g) * 16) ^ ((row & 7) << 4);
        short8v kf = *(const short8v*)((const char*)Ks + baddr);
        s = MFMA32(kf, ks ? qf1 : qf0, s);
      }
      st[jt] = s;
    }

    float sv[8];
#pragma unroll
    for (int jt = 0; jt < 2; jt++)
#pragma unroll
      for (int r = 0; r < 4; r++) sv[jt * 4 + r] = st[jt][r] * csc;
    float tm = sv[0];
#pragma unroll
    for (int i = 1; i < 8; i++) tm = fmaxf(tm, sv[i]);
    tm = fmaxf(tm, __shfl_xor(tm, 16));
    tm = fmaxf(tm, __shfl_xor(tm, 32));
    const float mnew = fmaxf(mrun, tm);
    const float sca = exp2f(mrun - mnew);
    mrun = mnew;
    float p[8];
    float ts = 0.f;
#pragma unroll
    for (int i = 0; i < 8; i++) {
      p[i] = exp2f(sv[i] - mnew);
      ts += p[i];
    }
    ts += __shfl_xor(ts, 16);
    ts += __shfl_xor(ts, 32);
    lsum = lsum * sca + ts;
#pragma unroll
    for (int d = 0; d < 4; d++)
#pragma unroll
      for (int r = 0; r < 4; r++) ot[d][r] *= sca;

    short4v pf[2];
#pragma unroll
    for (int jt = 0; jt < 2; jt++) {
      short4v pq;
#pragma unroll
      for (int r = 0; r < 4; r++) pq[r] = (short)f2bf(p[jt * 4 + r]);
      pf[jt] = pq;
    }

#pragma unroll
    for (int jt = 0; jt < 2; jt++)
#pragma unroll
      for (int dblk = 0; dblk < 4; dblk++) {
        short4v vfr;
#pragma unroll
        for (int jj = 0; jj < 4; jj++) {
          const int j = jt * 16 + g * 4 + jj;
          const int dsw = (dblk * 16 + lr) ^ (g << 4);
          vfr[jj] = (short)Vs[j * 64 + dsw];
        }
        ot[dblk] = MFMA16(vfr, pf[jt], ot[dblk]);
      }
  }

  const float inv = 1.f / lsum;
  u16* Op = Om + ((size_t)(b * 1024 + qrow)) * 1024 + a * 64;
#pragma unroll
  for (int dblk = 0; dblk < 4; dblk++) {
    short4v o4;
#pragma unroll
    for (int r = 0; r < 4; r++) o4[r] = (short)f2bf(ot[dblk][r] * inv);
    *(short4v*)(Op + dblk * 16 + g * 4) = o4;
  }
}

// ---------------- launch ----------------

extern "C" void kernel_launch(void* const* d_in, const int* in_sizes, int n_in,
                              void* d_out, int out_size, void* d_ws, size_t ws_size,
                              hipStream_t stream) {
  (void)in_sizes; (void)n_in; (void)out_size; (void)ws_size;
  const float* x = (const float*)d_in[0];
  const float* Wq = (const float*)d_in[1];
  const float* bq = (const float*)d_in[2];
  const float* Wk = (const float*)d_in[3];
  const float* bk = (const float*)d_in[4];
  const float* Wv = (const float*)d_in[5];
  const float* bv = (const float*)d_in[6];
  const float* Wo = (const float*)d_in[7];
  const float* bo = (const float*)d_in[8];
  float* out = (float*)d_out;

  char* ws = (char*)d_ws;
  const size_t MB = 1u << 20;
  u16* xb = (u16*)(ws + 0 * MB);    // 4096x1024 bf16 (8MB)
  u16* Wqb = (u16*)(ws + 8 * MB);   // 2MB each
  u16* Wkb = (u16*)(ws + 10 * MB);
  u16* Wvb = (u16*)(ws + 12 * MB);
  u16* Wob = (u16*)(ws + 14 * MB);
  u16* Qb = (u16*)(ws + 16 * MB);   // 8MB each
  u16* Kb = (u16*)(ws + 24 * MB);
  u16* Vb = (u16*)(ws + 32 * MB);
  u16* Ab = (u16*)(ws + 40 * MB);   // attention out bf16

  cast1_k<<<4096, 256, 0, stream>>>(x, xb);
  cast4_k<<<dim3(1024, 4), 256, 0, stream>>>(Wq, Wk, Wv, Wo, Wqb, Wkb, Wvb, Wob);
  gemm_bt<0><<<dim3(32, 24), 256, 0, stream>>>(xb, Wqb, Wkb, Wvb, bq, bk, bv, Qb, Kb, Vb);
  attn_fwd<<<dim3(16, 64), 256, 0, stream>>>(Qb, Kb, Vb, Ab);
  gemm_bt<1><<<dim3(32, 8), 256, 0, stream>>>(Ab, Wob, Wob, Wob, bo, bo, bo, out, out, out);
}

// Round 2
// 187.984 us; speedup vs baseline: 1.0846x; 1.0846x over previous
//
#include <hip/hip_runtime.h>
#include <stdint.h>

typedef unsigned short u16;
typedef short short4v __attribute__((ext_vector_type(4)));
typedef short short8v __attribute__((ext_vector_type(8)));
typedef float float4v __attribute__((ext_vector_type(4)));

#define AS1(p) ((__attribute__((address_space(1))) void*)(p))
#define AS3(p) ((__attribute__((address_space(3))) void*)(p))

#define MFMA32(a, b, c) __builtin_amdgcn_mfma_f32_16x16x32_bf16(a, b, c, 0, 0, 0)

static __device__ __forceinline__ float4v MFMA16(short4v a, short4v b, float4v c) {
#if __has_builtin(__builtin_amdgcn_mfma_f32_16x16x16bf16_1k)
  return __builtin_amdgcn_mfma_f32_16x16x16bf16_1k(a, b, c, 0, 0, 0);
#else
  float4v d;
  asm volatile("v_mfma_f32_16x16x16_bf16 %0, %1, %2, %3\n\ts_nop 7\n\ts_nop 3"
               : "=v"(d)
               : "v"(a), "v"(b), "v"(c));
  return d;
#endif
}

static __device__ __forceinline__ u16 f2bf(float f) {
  uint32_t u = __builtin_bit_cast(uint32_t, f);
  u += 0x7FFFu + ((u >> 16) & 1u);
  return (u16)(u >> 16);
}

static __device__ __forceinline__ unsigned cvtpk(float lo, float hi) {
  unsigned r;
  asm("v_cvt_pk_bf16_f32 %0, %1, %2" : "=v"(r) : "v"(lo), "v"(hi));
  return r;
}

// 4 hardware-transpose V-fragment reads + wait, fused in one asm block so the
// compiler cannot reorder MFMA consumers above the lgkmcnt (rule #18).
#define TR4(v0_, v1_, v2_, v3_, addr_)                                   \
  asm volatile("ds_read_b64_tr_b16 %0, %4 offset:0\n\t"                  \
               "ds_read_b64_tr_b16 %1, %4 offset:2048\n\t"               \
               "ds_read_b64_tr_b16 %2, %4 offset:4096\n\t"               \
               "ds_read_b64_tr_b16 %3, %4 offset:6144\n\t"               \
               "s_waitcnt lgkmcnt(0)"                                    \
               : "=&v"(v0_), "=&v"(v1_), "=&v"(v2_), "=&v"(v3_)          \
               : "v"(addr_)                                              \
               : "memory")

// ---------------- f32 -> bf16 casts ----------------

__global__ __launch_bounds__(256) void cast1_k(const float* __restrict__ s, u16* __restrict__ d) {
  const int i = (blockIdx.x * 256 + threadIdx.x) * 4;
  float4v v = *(const float4v*)(s + i);
  short4v o;
#pragma unroll
  for (int j = 0; j < 4; j++) o[j] = (short)f2bf(v[j]);
  *(short4v*)(d + i) = o;
}

__global__ __launch_bounds__(256) void cast4_k(const float* __restrict__ s0, const float* __restrict__ s1,
                                               const float* __restrict__ s2, const float* __restrict__ s3,
                                               u16* __restrict__ d0, u16* __restrict__ d1,
                                               u16* __restrict__ d2, u16* __restrict__ d3) {
  const float* s;
  u16* d;
  switch (blockIdx.y) {
    case 0: s = s0; d = d0; break;
    case 1: s = s1; d = d1; break;
    case 2: s = s2; d = d2; break;
    default: s = s3; d = d3; break;
  }
  const int i = (blockIdx.x * 256 + threadIdx.x) * 4;
  float4v v = *(const float4v*)(s + i);
  short4v o;
#pragma unroll
  for (int j = 0; j < 4; j++) o[j] = (short)f2bf(v[j]);
  *(short4v*)(d + i) = o;
}

// ---------------- GEMM: C[m,n] = (sum_k A[m,k]*B[n,k] + bias[n]) * scale ----------------
// 128x128 tile, BK=32, 2-phase double-buffered LDS (T3-minimum).

template <int OUTF32>
__global__ __launch_bounds__(256) void gemm_bt(
    const u16* __restrict__ A,
    const u16* __restrict__ B0, const u16* __restrict__ B1, const u16* __restrict__ B2,
    const float* __restrict__ bias0, const float* __restrict__ bias1, const float* __restrict__ bias2,
    void* __restrict__ C0, void* __restrict__ C1, void* __restrict__ C2,
    float sc0, float sc1, float sc2) {
  constexpr int K = 1024;
  __shared__ u16 As[2][128 * 32];
  __shared__ u16 Bs[2][128 * 32];

  const int t = threadIdx.x;
  const int lane = t & 63, wid = t >> 6;
  const int wr = wid >> 1, wc = wid & 1;
  const int lr = lane & 15, g = lane >> 4;

  const int seg = blockIdx.y >> 3, nb = blockIdx.y & 7, mb = blockIdx.x;
  const u16* B = seg == 0 ? B0 : (seg == 1 ? B1 : B2);
  const float* bias = seg == 0 ? bias0 : (seg == 1 ? bias1 : bias2);
  void* C = seg == 0 ? C0 : (seg == 1 ? C1 : C2);
  const float scale = seg == 0 ? sc0 : (seg == 1 ? sc1 : sc2);

  const u16* Ap = A + (size_t)mb * 128 * K;
  const u16* Bp = B + (size_t)nb * 128 * K;

  float4v z = {0.f, 0.f, 0.f, 0.f};
  float4v acc[4][4];
#pragma unroll
  for (int i = 0; i < 4; i++)
#pragma unroll
    for (int j = 0; j < 4; j++) acc[i][j] = z;

  const int r0 = t >> 2, c0 = (t & 3) * 8;

#define GSTAGE(u, kk)                                                                                          \
  do {                                                                                                         \
    __builtin_amdgcn_global_load_lds(AS1(Ap + (size_t)r0 * K + (kk) + c0), AS3(&As[u][t * 8]), 16, 0, 0);      \
    __builtin_amdgcn_global_load_lds(AS1(Ap + (size_t)(r0 + 64) * K + (kk) + c0), AS3(&As[u][(t + 256) * 8]),  \
                                     16, 0, 0);                                                                \
    __builtin_amdgcn_global_load_lds(AS1(Bp + (size_t)r0 * K + (kk) + c0), AS3(&Bs[u][t * 8]), 16, 0, 0);      \
    __builtin_amdgcn_global_load_lds(AS1(Bp + (size_t)(r0 + 64) * K + (kk) + c0), AS3(&Bs[u][(t + 256) * 8]),  \
                                     16, 0, 0);                                                                \
  } while (0)

  GSTAGE(0, 0);
  int cur = 0;
  for (int k0 = 0; k0 < K; k0 += 32) {
    __syncthreads();  // drains vmcnt -> buf[cur] ready
    if (k0 + 32 < K) GSTAGE(cur ^ 1, k0 + 32);

    const u16* Au = &As[cur][0];
    const u16* Bu = &Bs[cur][0];
    short8v af[4], bfr[4];
#pragma unroll
    for (int mi = 0; mi < 4; mi++) af[mi] = *(const short8v*)(Au + (wr * 64 + mi * 16 + lr) * 32 + g * 8);
#pragma unroll
    for (int ni = 0; ni < 4; ni++) bfr[ni] = *(const short8v*)(Bu + (wc * 64 + ni * 16 + lr) * 32 + g * 8);
    __builtin_amdgcn_s_setprio(1);
#pragma unroll
    for (int mi = 0; mi < 4; mi++)
#pragma unroll
      for (int ni = 0; ni < 4; ni++) acc[mi][ni] = MFMA32(af[mi], bfr[ni], acc[mi][ni]);
    __builtin_amdgcn_s_setprio(0);
    __syncthreads();
    cur ^= 1;
  }
#undef GSTAGE

  const int colb = nb * 128 + wc * 64;
  const int rowb = mb * 128 + wr * 64;
#pragma unroll
  for (int ni = 0; ni < 4; ni++) {
    const int col = colb + ni * 16 + lr;
    const float bv = bias[col];
#pragma unroll
    for (int mi = 0; mi < 4; mi++) {
      const int row0 = rowb + mi * 16 + g * 4;
      float4v a = acc[mi][ni];
      if (OUTF32) {
        float* Cf = (float*)C;
#pragma unroll
        for (int r = 0; r < 4; r++) Cf[(size_t)(row0 + r) * 1024 + col] = (a[r] + bv) * scale;
      } else {
        u16* Cb = (u16*)C;
#pragma unroll
        for (int r = 0; r < 4; r++) Cb[(size_t)(row0 + r) * 1024 + col] = f2bf((a[r] + bv) * scale);
      }
    }
  }
}

// ---------------- Flash attention ----------------
// KVBLK=64, double-buffered. Q pre-scaled by log2(e)/sqrt(64) in the QKV GEMM.
// S^T = mfma(K,Q) so each lane owns 16 P-values of one q-row; softmax reduce =
// in-register + 2 shfl_xor. PV via mfma16 with V^T A-frags from ds_read_b64_tr_b16
// out of a [dblk][64][16] subtiled V (linear LDS dest, permuted global source).

__global__ __launch_bounds__(256) void attn_fwd(const u16* __restrict__ Qm, const u16* __restrict__ Km,
                                                const u16* __restrict__ Vm, u16* __restrict__ Om) {
  __shared__ u16 Ks[2][64 * 64];
  __shared__ u16 Vs[2][64 * 64];

  const int t = threadIdx.x;
  const int lane = t & 63, w = t >> 6;
  const int lr = lane & 15, g = lane >> 4;
  const int qb = blockIdx.x, pair = blockIdx.y;
  const int b = pair >> 4, a = pair & 15;

  const int qrow = qb * 64 + w * 16 + lr;
  const size_t qoff = ((size_t)(b * 1024 + qrow)) * 1024 + a * 64;
  const short8v qf0 = *(const short8v*)(Qm + qoff + g * 8);
  const short8v qf1 = *(const short8v*)(Qm + qoff + 32 + g * 8);

  float4v z = {0.f, 0.f, 0.f, 0.f};
  float4v ot[4];
#pragma unroll
  for (int i = 0; i < 4; i++) ot[i] = z;
  float mrun = -3.0e38f, lsum = 0.f;

  const u16* Kb = Km + ((size_t)b * 1024) * 1024 + a * 64;
  const u16* Vb = Vm + ((size_t)b * 1024) * 1024 + a * 64;

  // K staging: chunk cidx -> row=cidx>>3, physical col-chunk c=cidx&7 holds logical chunk c^(row&7)
  const int kr0 = t >> 3, kr1 = kr0 + 32;
  const int kc0 = ((t & 7) ^ (kr0 & 7)) * 8;  // (kr1&7)==(kr0&7) so same for chunk 2
  // V staging: chunk cidx -> dblk=cidx>>7, row=(cidx>>1)&63, half=cidx&1
  const int vr0 = (t >> 1) & 63;
  const int vc0 = (t >> 7) * 16 + (t & 1) * 8;  // second chunk: +32 (dblk+2)

#define ASTAGE(u, kt)                                                                                             \
  do {                                                                                                            \
    __builtin_amdgcn_global_load_lds(AS1(Kb + (size_t)((kt) + kr0) * 1024 + kc0), AS3(&Ks[u][t * 8]), 16, 0, 0);  \
    __builtin_amdgcn_global_load_lds(AS1(Kb + (size_t)((kt) + kr1) * 1024 + kc0), AS3(&Ks[u][(t + 256) * 8]),     \
                                     16, 0, 0);                                                                   \
    __builtin_amdgcn_global_load_lds(AS1(Vb + (size_t)((kt) + vr0) * 1024 + vc0), AS3(&Vs[u][t * 8]), 16, 0, 0);  \
    __builtin_amdgcn_global_load_lds(AS1(Vb + (size_t)((kt) + vr0) * 1024 + vc0 + 32), AS3(&Vs[u][(t + 256) * 8]),\
                                     16, 0, 0);                                                                   \
  } while (0)

  // tr-read lane address part: lane (g,lr) -> (g*4 + (lr>>2))*32 + (lane&3)*8 bytes
  const unsigned vsbase = (unsigned)(uintptr_t)AS3(&Vs[0][0]);
  const unsigned vlane = (unsigned)((g * 4 + (lr >> 2)) * 32 + (lane & 3) * 8);

  ASTAGE(0, 0);
  int cur = 0;
  for (int kt = 0; kt < 1024; kt += 64) {
    __syncthreads();  // buf[cur] ready (compiler drains vmcnt before barrier)
    if (kt + 64 < 1024) ASTAGE(cur ^ 1, kt + 64);

    // ---- S^T = K * Q^T : 4 tiles of (16 kr x 16 q) ----
    const u16* Ku = &Ks[cur][0];
    float4v st[4];
#pragma unroll
    for (int jt = 0; jt < 4; jt++) {
      float4v s = z;
      const int row = jt * 16 + lr;
      const int rsw = (row & 7) << 4;
      __builtin_amdgcn_s_setprio(1);
#pragma unroll
      for (int ks = 0; ks < 2; ks++) {
        const int baddr = (row * 128 + (ks * 4 + g) * 16) ^ rsw;
        short8v kf = *(const short8v*)((const char*)Ku + baddr);
        s = MFMA32(kf, ks ? qf1 : qf0, s);
      }
      __builtin_amdgcn_s_setprio(0);
      st[jt] = s;
    }

    // ---- online softmax (values already in log2 domain, pre-scaled) ----
    float tm = st[0][0];
#pragma unroll
    for (int jt = 0; jt < 4; jt++)
#pragma unroll
      for (int r = 0; r < 4; r++) tm = fmaxf(tm, st[jt][r]);
    tm = fmaxf(tm, __shfl_xor(tm, 16));
    tm = fmaxf(tm, __shfl_xor(tm, 32));
    if (!__all(tm - mrun <= 8.f)) {  // T13 defer-max: skip rescale when growth small
      const float mnew = fmaxf(mrun, tm);
      const float sca = exp2f(mrun - mnew);
      lsum *= sca;
#pragma unroll
      for (int d = 0; d < 4; d++)
#pragma unroll
        for (int r = 0; r < 4; r++) ot[d][r] *= sca;
      mrun = mnew;
    }
    float p[16];
    float ts = 0.f;
#pragma unroll
    for (int jt = 0; jt < 4; jt++)
#pragma unroll
      for (int r = 0; r < 4; r++) {
        const float pv = exp2f(st[jt][r] - mrun);
        p[jt * 4 + r] = pv;
        ts += pv;
      }
    ts += __shfl_xor(ts, 16);
    ts += __shfl_xor(ts, 32);
    lsum += ts;

    short4v pf[4];
#pragma unroll
    for (int jt = 0; jt < 4; jt++) {
      unsigned lo = cvtpk(p[jt * 4 + 0], p[jt * 4 + 1]);
      unsigned hi = cvtpk(p[jt * 4 + 2], p[jt * 4 + 3]);
      unsigned u2[2] = {lo, hi};
      pf[jt] = __builtin_bit_cast(short4v, *(unsigned long long*)u2);
    }

    // ---- PV: O^T += V^T * P^T ----
    unsigned va = vsbase + (unsigned)cur * 8192u + vlane;
#pragma unroll
    for (int jt = 0; jt < 4; jt++) {
      short4v vf0, vf1, vf2, vf3;
      TR4(vf0, vf1, vf2, vf3, va);
      __builtin_amdgcn_s_setprio(1);
      ot[0] = MFMA16(vf0, pf[jt], ot[0]);
      ot[1] = MFMA16(vf1, pf[jt], ot[1]);
      ot[2] = MFMA16(vf2, pf[jt], ot[2]);
      ot[3] = MFMA16(vf3, pf[jt], ot[3]);
      __builtin_amdgcn_s_setprio(0);
      va += 512u;
    }

    __syncthreads();
    cur ^= 1;
  }
#undef ASTAGE

  const float inv = 1.f / lsum;
  u16* Op = Om + ((size_t)(b * 1024 + qrow)) * 1024 + a * 64;
#pragma unroll
  for (int dblk = 0; dblk < 4; dblk++) {
    short4v o4;
#pragma unroll
    for (int r = 0; r < 4; r++) o4[r] = (short)f2bf(ot[dblk][r] * inv);
    *(short4v*)(Op + dblk * 16 + g * 4) = o4;
  }
}

// ---------------- launch ----------------

extern "C" void kernel_launch(void* const* d_in, const int* in_sizes, int n_in,
                              void* d_out, int out_size, void* d_ws, size_t ws_size,
                              hipStream_t stream) {
  (void)in_sizes; (void)n_in; (void)out_size; (void)ws_size;
  const float* x = (const float*)d_in[0];
  const float* Wq = (const float*)d_in[1];
  const float* bq = (const float*)d_in[2];
  const float* Wk = (const float*)d_in[3];
  const float* bk = (const float*)d_in[4];
  const float* Wv = (const float*)d_in[5];
  const float* bv = (const float*)d_in[6];
  const float* Wo = (const float*)d_in[7];
  const float* bo = (const float*)d_in[8];
  float* out = (float*)d_out;

  char* ws = (char*)d_ws;
  const size_t MB = 1u << 20;
  u16* xb = (u16*)(ws + 0 * MB);
  u16* Wqb = (u16*)(ws + 8 * MB);
  u16* Wkb = (u16*)(ws + 10 * MB);
  u16* Wvb = (u16*)(ws + 12 * MB);
  u16* Wob = (u16*)(ws + 14 * MB);
  u16* Qb = (u16*)(ws + 16 * MB);
  u16* Kb = (u16*)(ws + 24 * MB);
  u16* Vb = (u16*)(ws + 32 * MB);
  u16* Ab = (u16*)(ws + 40 * MB);

  const float csc = 1.4426950408889634f / 8.0f;  // log2(e)/sqrt(HEAD_DIM)

  cast1_k<<<4096, 256, 0, stream>>>(x, xb);
  cast4_k<<<dim3(1024, 4), 256, 0, stream>>>(Wq, Wk, Wv, Wo, Wqb, Wkb, Wvb, Wob);
  gemm_bt<0><<<dim3(32, 24), 256, 0, stream>>>(xb, Wqb, Wkb, Wvb, bq, bk, bv, Qb, Kb, Vb, csc, 1.f, 1.f);
  attn_fwd<<<dim3(16, 64), 256, 0, stream>>>(Qb, Kb, Vb, Ab);
  gemm_bt<1><<<dim3(32, 8), 256, 0, stream>>>(Ab, Wob, Wob, Wob, bo, bo, bo, out, out, out, 1.f, 1.f, 1.f);
}